// Round 6
// baseline (121.180 us; speedup 1.0000x reference)
//
#include <hip/hip_runtime.h>
#include <stdint.h>

#pragma clang fp contract(off)

typedef __attribute__((ext_vector_type(4))) int i32x4;
typedef __attribute__((ext_vector_type(16))) int i32x16;

#define B_    16
#define C_    128
#define HW_   56
#define L_    3136      // 56*56
#define CO_   128
#define F_    1152      // 128*9
#define M_    50176     // 16*3136

// ---- workspace layout (bytes) ----
#define OFF_SW   256        // float scale_w[128]
#define OFF_ZPW  768        // int   zp_w[128]
#define OFF_CT   1280       // int   const_term[128]
#define OFF_QW   4096       // int8  qw2[j][ch][o][16] = 9*8*128*16 = 147456
#define OFF_QX   153600     // int8  qx_t[b][l][c] = 6422528 (channel-last)
#define OFF_S    6576128    // int   S[b][3136] channel-sums = 200704 (end ~6.8MB)

#define HALO_BYTES (6*58*128)                  // 44544
#define BS_BYTES   16384
#define POOL_BYTES (HALO_BYTES + 2*BS_BYTES)   // 77312

struct QP { unsigned xmin_enc, xmax_enc; int rmin, rmax; };

__device__ __forceinline__ unsigned enc_f(float f) {
    unsigned u = __float_as_uint(f);
    return (u & 0x80000000u) ? ~u : (u | 0x80000000u);
}
__device__ __forceinline__ float dec_f(unsigned e) {
    return __uint_as_float((e & 0x80000000u) ? (e ^ 0x80000000u) : ~e);
}
__device__ __forceinline__ int read_abit(const int* p) {
    int i = *p;
    if (i > 0 && i < 32) return i;
    float f = __int_as_float(i);
    int fi = (int)f;
    return (fi > 0 && fi < 32) ? fi : 8;
}
__device__ __forceinline__ void get_sx(const QP* P, int abit, float& sx, float& zx) {
    float xmin = dec_f(P->xmin_enc), xmax = dec_f(P->xmax_enc);
    float n = (float)((1 << abit) - 1);
    sx = n / fmaxf(xmax - xmin, 1e-8f);
    zx = rintf(sx * xmin) + (float)(1 << (abit - 1));
}

// ---------------- kernels ----------------

__global__ void k_init(char* ws) {
    if (threadIdx.x == 0) {
        QP* P = (QP*)ws;
        P->xmin_enc = 0x80000000u;  // enc(0.0f): padding zeros count
        P->xmax_enc = 0x80000000u;
        P->rmin = INT32_MAX;
        P->rmax = INT32_MIN;
    }
}

__global__ void k_xminmax(const float4* __restrict__ x4, int n4, char* ws) {
    QP* P = (QP*)ws;
    float mn = 0.0f, mx = 0.0f;
    int stride = gridDim.x * blockDim.x;
    for (int i = blockIdx.x * blockDim.x + threadIdx.x; i < n4; i += stride) {
        float4 v = x4[i];
        mn = fminf(mn, fminf(fminf(v.x, v.y), fminf(v.z, v.w)));
        mx = fmaxf(mx, fmaxf(fmaxf(v.x, v.y), fmaxf(v.z, v.w)));
    }
    for (int m = 32; m; m >>= 1) {
        mn = fminf(mn, __shfl_xor(mn, m));
        mx = fmaxf(mx, __shfl_xor(mx, m));
    }
    __shared__ float smn[4], smx[4];
    int w = threadIdx.x >> 6;
    if ((threadIdx.x & 63) == 0) { smn[w] = mn; smx[w] = mx; }
    __syncthreads();
    if (threadIdx.x == 0) {
        mn = fminf(fminf(smn[0], smn[1]), fminf(smn[2], smn[3]));
        mx = fmaxf(fmaxf(smx[0], smx[1]), fmaxf(smx[2], smx[3]));
        atomicMin(&P->xmin_enc, enc_f(mn));
        atomicMax(&P->xmax_enc, enc_f(mx));
    }
}

// one wave per output channel; packs qw2[j][ch][o][16]  (ch = c>>4, byte = c&15)
__global__ void k_wquant(const float* __restrict__ w, const float* __restrict__ bias,
                         const int* __restrict__ abit_p, char* ws) {
    QP* P = (QP*)ws;
    float* scale_w = (float*)(ws + OFF_SW);
    int* zpw = (int*)(ws + OFF_ZPW);
    int* ct  = (int*)(ws + OFF_CT);
    signed char* qw = (signed char*)(ws + OFF_QW);

    int o = blockIdx.x, lane = threadIdx.x;
    const float* wr = w + o * F_;
    float mn = 3.4e38f, mx = -3.4e38f;
    for (int f = lane; f < F_; f += 64) {
        float v = wr[f];
        mn = fminf(mn, v); mx = fmaxf(mx, v);
    }
    for (int m = 32; m; m >>= 1) {
        mn = fminf(mn, __shfl_xor(mn, m));
        mx = fmaxf(mx, __shfl_xor(mx, m));
    }
    float sw = 255.0f / fmaxf(mx - mn, 1e-8f);
    float zw = rintf(sw * mn) + 128.0f;

    int qsum = 0;
    for (int f = lane; f < F_; f += 64) {
        float q = fminf(fmaxf(rintf(sw * wr[f] - zw), -128.0f), 127.0f);
        int qi = (int)q;
        qsum += qi;
        int c = f / 9, j = f - c * 9;
        qw[j * 16384 + (c >> 4) * 2048 + (o << 4) + (c & 15)] = (signed char)qi;
    }
    for (int m = 32; m; m >>= 1) qsum += __shfl_xor(qsum, m);
    if (lane == 0) {
        int abit = read_abit(abit_p);
        float sx, zx; get_sx(P, abit, sx, zx);
        float qb = rintf(sw * sx * bias[o]);
        int zwi = (int)zw, zxi = (int)zx;
        ct[o] = zxi * qsum + F_ * zwi * zxi + (int)qb;
        zpw[o] = zwi;
        scale_w[o] = sw;
    }
}

// quantize to channel-last qx_t[b][l][c] + per-pixel channel sums S[b][l]
__global__ __launch_bounds__(256) void k_xquant(const float* __restrict__ x,
                                                const int* __restrict__ abit_p, char* ws) {
    __shared__ int ssum[4][64];
    QP* P = (QP*)ws;
    int abit = read_abit(abit_p);
    float sx, zx; get_sx(P, abit, sx, zx);
    int nx = 1 << (abit - 1);
    float lo = -(float)nx, hif = (float)(nx - 1);
    signed char* qxt = (signed char*)(ws + OFF_QX);
    int gid = blockIdx.x;
    int b = gid / 49, lcq = gid - b * 49;
    int l0 = lcq * 64;
    int t = threadIdx.x;
    int lane = t & 63, cg = t >> 6;
    int l = l0 + lane;
    const float* xb = x + ((size_t)b * C_) * L_ + l;
    int4* dst = (int4*)(qxt + ((size_t)(b * L_ + l)) * 128);
    int psum = 0;
    #pragma unroll
    for (int ii = 0; ii < 2; ++ii) {
        int c16 = (cg + 4 * ii) * 16;
        int wds[4];
        #pragma unroll
        for (int k = 0; k < 4; ++k) {
            int wv = 0;
            #pragma unroll
            for (int e = 0; e < 4; ++e) {
                int c = c16 + 4 * k + e;
                float v = xb[(size_t)c * L_];
                int qi = (int)fminf(fmaxf(rintf(sx * v - zx), lo), hif);
                psum += qi;
                wv |= (qi & 255) << (8 * e);
            }
            wds[k] = wv;
        }
        int4 vv; vv.x = wds[0]; vv.y = wds[1]; vv.z = wds[2]; vv.w = wds[3];
        dst[c16 >> 4] = vv;
    }
    ssum[cg][lane] = psum;
    __syncthreads();
    if (cg == 0) {
        int* S = (int*)(ws + OFF_S);
        S[b * L_ + l] = ssum[0][lane] + ssum[1][lane] + ssum[2][lane] + ssum[3][lane];
    }
}

// 128M x 128N MFMA int8 GEMM. 4 waves as 2Mx2N, each 64Mx64N (acc[2][2]).
// A: 6x58x128 halo staged once (XOR swizzle). B: per-tap 16KB LDS tile,
// reg-staged double-buffer, global loads issued one tap ahead.
// PASS 1: global res min/max. PASS 2: requant+dequant + transpose + store.
template <int PASS>
__global__ __launch_bounds__(256, 2) void k_gemm(const int* __restrict__ abit_p,
                                                 char* __restrict__ ws,
                                                 float* __restrict__ out) {
    __shared__ __align__(16) char pool[POOL_BYTES];
    __shared__ int S_s[6 * 58];
    __shared__ int sq_s[128];
    __shared__ int red[8];

    QP* P = (QP*)ws;
    const signed char* qxt = (const signed char*)(ws + OFF_QX);
    const signed char* qw  = (const signed char*)(ws + OFF_QW);
    const int* Sg    = (const int*)(ws + OFF_S);
    const int* zpw   = (const int*)(ws + OFF_ZPW);
    const int* ct    = (const int*)(ws + OFF_CT);
    const float* scale_w = (const float*)(ws + OFF_SW);

    signed char* NB  = (signed char*)pool;
    signed char* Bs0 = (signed char*)(pool + HALO_BYTES);
    signed char* Bs1 = Bs0 + BS_BYTES;

    int t = threadIdx.x;
    int blk = blockIdx.x;
    int b = blk / 25, kb = blk - b * 25;     // 25 tiles of 128 rows (last half-masked)
    int l0 = kb << 7;
    int prow0 = l0 / HW_;

    int abit = read_abit(abit_p);
    float sx, zx; get_sx(P, abit, sx, zx);
    int nx = 1 << (abit - 1);
    int q0 = min(max(-(int)zx, -nx), nx - 1);
    int pw = (q0 & 255) * 0x01010101;
    int4 pad4; pad4.x = pw; pad4.y = pw; pad4.z = pw; pad4.w = pw;
    int padS = C_ * q0;

    const signed char* qxtb = qxt + (size_t)b * L_ * 128;
    const int* Sb = Sg + b * L_;

    // issue tap0 B loads (64 B/thread, coalesced)
    int4 breg[4];
    {
        const int4* src = (const int4*)qw + t * 4;
        breg[0] = src[0]; breg[1] = src[1]; breg[2] = src[2]; breg[3] = src[3];
    }

    // stage A halo: 6 rows x 58 pix x 8 chunks = 2784 slots, swizzle ch ^= pix&7
    #pragma unroll
    for (int i = 0; i < 11; ++i) {
        int slot = t + i * 256;
        if (slot < 2784) {
            int pix = slot >> 3, ch = slot & 7;
            int ri = pix / 58, c1 = pix - ri * 58;
            int ih = prow0 - 1 + ri, iw = c1 - 1;
            int4 v = pad4;
            if ((unsigned)ih < HW_ && (unsigned)iw < HW_)
                v = *(const int4*)(qxtb + ((ih * HW_ + iw) << 7) + (ch << 4));
            *(int4*)&NB[(pix << 7) + ((ch ^ (pix & 7)) << 4)] = v;
        }
    }
    // stage S halo (348 entries)
    #pragma unroll
    for (int i = 0; i < 2; ++i) {
        int slot = t + i * 256;
        if (slot < 348) {
            int ri = slot / 58, c1 = slot - ri * 58;
            int ih = prow0 - 1 + ri, iw = c1 - 1;
            S_s[slot] = ((unsigned)ih < HW_ && (unsigned)iw < HW_) ? Sb[ih * HW_ + iw] : padS;
        }
    }
    // write Bs0, issue tap1 loads
    {
        int4* d = (int4*)Bs0 + t * 4;
        d[0] = breg[0]; d[1] = breg[1]; d[2] = breg[2]; d[3] = breg[3];
        const int4* src = (const int4*)(qw + BS_BYTES) + t * 4;
        breg[0] = src[0]; breg[1] = src[1]; breg[2] = src[2]; breg[3] = src[3];
    }
    __syncthreads();

    // per-row 3x3 box sums from S_s
    if (t < 128) {
        int l_loc = l0 + t; if (l_loc > L_ - 1) l_loc = L_ - 1;
        int oh = l_loc / HW_, ow = l_loc - oh * HW_;
        int ri = oh - prow0 + 1, ci = ow + 1;
        int s = 0;
        #pragma unroll
        for (int dr = -1; dr <= 1; ++dr)
            #pragma unroll
            for (int dc = -1; dc <= 1; ++dc)
                s += S_s[(ri + dr) * 58 + ci + dc];
        sq_s[t] = s;
    }

    int lane = t & 63, w = t >> 6;
    int wm = (w >> 1) << 6;            // 0 / 64
    int wn = (w & 1) << 6;             // 0 / 64
    int r = lane & 31, hi = lane >> 5;

    int pbase[2];
    #pragma unroll
    for (int mi = 0; mi < 2; ++mi) {
        int l_loc = l0 + wm + mi * 32 + r;
        if (l_loc > L_ - 1) l_loc = L_ - 1;
        int oh = l_loc / HW_, ow = l_loc - oh * HW_;
        pbase[mi] = (oh - prow0 + 1) * 58 + (ow + 1);
    }

    i32x16 acc00, acc01, acc10, acc11;
    #pragma unroll
    for (int i = 0; i < 16; ++i) { acc00[i] = 0; acc01[i] = 0; acc10[i] = 0; acc11[i] = 0; }

    #pragma unroll
    for (int j = 0; j < 9; ++j) {
        const signed char* Bcur = (j & 1) ? Bs1 : Bs0;
        const int dj = (j / 3 - 1) * 58 + (j % 3 - 1);
        i32x4 af[2][4], bf[2][4];
        #pragma unroll
        for (int ch = 0; ch < 4; ++ch) {
            int ch2 = ch * 2 + hi;
            #pragma unroll
            for (int mi = 0; mi < 2; ++mi) {
                int pix = pbase[mi] + dj;
                af[mi][ch] = *(const i32x4*)&NB[(pix << 7) + ((ch2 ^ (pix & 7)) << 4)];
            }
            #pragma unroll
            for (int ni = 0; ni < 2; ++ni)
                bf[ni][ch] = *(const i32x4*)&Bcur[ch2 * 2048 + ((wn + ni * 32 + r) << 4)];
        }
        #pragma unroll
        for (int ch = 0; ch < 4; ++ch) {
            acc00 = __builtin_amdgcn_mfma_i32_32x32x32_i8(af[0][ch], bf[0][ch], acc00, 0, 0, 0);
            acc01 = __builtin_amdgcn_mfma_i32_32x32x32_i8(af[0][ch], bf[1][ch], acc01, 0, 0, 0);
            acc10 = __builtin_amdgcn_mfma_i32_32x32x32_i8(af[1][ch], bf[0][ch], acc10, 0, 0, 0);
            acc11 = __builtin_amdgcn_mfma_i32_32x32x32_i8(af[1][ch], bf[1][ch], acc11, 0, 0, 0);
        }
        if (j < 8) {
            __syncthreads();
            int4* d = (int4*)((j & 1) ? Bs0 : Bs1) + t * 4;
            d[0] = breg[0]; d[1] = breg[1]; d[2] = breg[2]; d[3] = breg[3];
            if (j < 7) {
                const int4* src = (const int4*)(qw + (j + 2) * BS_BYTES) + t * 4;
                breg[0] = src[0]; breg[1] = src[1]; breg[2] = src[2]; breg[3] = src[3];
            }
            __syncthreads();
        }
    }

    int o0 = wn + r, o1 = wn + 32 + r;
    int zw0 = zpw[o0], c0 = ct[o0];
    int zw1 = zpw[o1], c1 = ct[o1];
    bool v0r = (l0 + wm) < L_;            // frag-row validity (32-row granular)
    bool v1r = (l0 + wm + 32) < L_;

    if (PASS == 1) {
        int lmin = INT32_MAX, lmax = INT32_MIN;
        #pragma unroll
        for (int mi = 0; mi < 2; ++mi) {
            if (mi == 0 ? !v0r : !v1r) continue;
            #pragma unroll
            for (int g = 0; g < 16; ++g) {
                int row = wm + mi * 32 + (g & 3) + ((g >> 2) << 3) + (hi << 2);
                int s = sq_s[row];
                int va = (mi == 0 ? acc00[g] : acc10[g]) + zw0 * s + c0;
                int vb = (mi == 0 ? acc01[g] : acc11[g]) + zw1 * s + c1;
                lmin = min(lmin, min(va, vb));
                lmax = max(lmax, max(va, vb));
            }
        }
        for (int m = 32; m; m >>= 1) {
            lmin = min(lmin, __shfl_xor(lmin, m));
            lmax = max(lmax, __shfl_xor(lmax, m));
        }
        if ((t & 63) == 0) { red[t >> 6] = lmin; red[4 + (t >> 6)] = lmax; }
        __syncthreads();
        if (t == 0) {
            lmin = min(min(red[0], red[1]), min(red[2], red[3]));
            lmax = max(max(red[4], red[5]), max(red[6], red[7]));
            atomicMin(&P->rmin, lmin);
            atomicMax(&P->rmax, lmax);
        }
    } else {
        float nlev = (float)((1 << abit) - 1);
        float rminf = (float)P->rmin, rmaxf = (float)P->rmax;
        float sr = nlev / fmaxf(rmaxf - rminf, 1e-8f);
        float zr = rintf(sr * rminf) + (float)nx;
        float lof = -(float)nx, hiq = (float)(nx - 1);
        float swsx0 = scale_w[o0] * sx;
        float swsx1 = scale_w[o1] * sx;
        float* tile = (float*)pool;        // [64][129] = 33024 B (aliases NB/Bs)

        #pragma unroll
        for (int rid = 0; rid < 2; ++rid) {
            __syncthreads();               // K-loop / previous-round reads done
            if (wm == rid * 64) {
                #pragma unroll
                for (int mi = 0; mi < 2; ++mi) {
                    #pragma unroll
                    for (int g = 0; g < 16; ++g) {
                        int rl = mi * 32 + (g & 3) + ((g >> 2) << 3) + (hi << 2);
                        int s = sq_s[wm + rl];
                        int va = (mi == 0 ? acc00[g] : acc10[g]) + zw0 * s + c0;
                        int vb = (mi == 0 ? acc01[g] : acc11[g]) + zw1 * s + c1;
                        float qa = fminf(fmaxf(rintf(sr * (float)va - zr), lof), hiq);
                        float qb = fminf(fmaxf(rintf(sr * (float)vb - zr), lof), hiq);
                        tile[rl * 129 + o0] = ((qa + zr) / sr) / swsx0;
                        tile[rl * 129 + o1] = ((qb + zr) / sr) / swsx1;
                    }
                }
            }
            __syncthreads();
            if (l0 + rid * 64 < L_) {      // skip masked half-tile
                int lbase = l0 + rid * 64;
                #pragma unroll
                for (int i = 0; i < 8; ++i) {
                    int o = (t >> 4) + i * 16;
                    int l4 = (t & 15) * 4;
                    float4 f;
                    #pragma unroll
                    for (int jj = 0; jj < 4; ++jj)
                        ((float*)&f)[jj] = tile[(l4 + jj) * 129 + o];
                    *(float4*)(out + ((size_t)(b * CO_ + o)) * L_ + lbase + l4) = f;
                }
            }
        }
    }
}

// ---------------- launch ----------------

extern "C" void kernel_launch(void* const* d_in, const int* in_sizes, int n_in,
                              void* d_out, int out_size, void* d_ws, size_t ws_size,
                              hipStream_t stream) {
    const float* x      = (const float*)d_in[0];
    const float* weight = (const float*)d_in[1];
    const float* bias   = (const float*)d_in[2];
    const int*   abit   = (const int*)d_in[3];
    float* out = (float*)d_out;
    char* ws = (char*)d_ws;

    int n4 = (B_ * C_ * L_) / 4;

    k_init<<<1, 64, 0, stream>>>(ws);
    k_xminmax<<<1024, 256, 0, stream>>>((const float4*)x, n4, ws);
    k_wquant<<<128, 64, 0, stream>>>(weight, bias, abit, ws);
    k_xquant<<<784, 256, 0, stream>>>(x, abit, ws);
    k_gemm<1><<<B_ * 25, 256, 0, stream>>>(abit, ws, nullptr);
    k_gemm<2><<<B_ * 25, 256, 0, stream>>>(abit, ws, out);
}